// Round 1
// baseline (795.738 us; speedup 1.0000x reference)
//
#include <hip/hip_runtime.h>
#include <stdint.h>
#include <math.h>

// ---------------- problem constants ----------------
#define B_N   16384
#define D_N   1024
#define K_N   512
#define U_N   2
#define KU_N  1024          // K*U
#define EPS_F 1e-8f
#define TEMP  0.67f         // both TEMP_BERN and TEMP_CAT
#define EULERC 0.5772156649015329f

// sizes of the random streams
#define NEPS  1048576       // D*KU
#define NU    524288        // D*K
#define NG    16777216      // B*K*U
#define HEPS  524288
#define HU    262144
#define HG    8388608

// ---------------- threefry2x32 (JAX-exact) ----------------
#define TF_ROT(x, r) (((x) << (r)) | ((x) >> (32 - (r))))

__host__ __device__ static inline void threefry2x32(uint32_t k0, uint32_t k1,
                                                    uint32_t x0, uint32_t x1,
                                                    uint32_t* o0, uint32_t* o1) {
  uint32_t ks2 = k0 ^ k1 ^ 0x1BD11BDAu;
  x0 += k0; x1 += k1;
  x0 += x1; x1 = TF_ROT(x1, 13); x1 ^= x0;
  x0 += x1; x1 = TF_ROT(x1, 15); x1 ^= x0;
  x0 += x1; x1 = TF_ROT(x1, 26); x1 ^= x0;
  x0 += x1; x1 = TF_ROT(x1, 6);  x1 ^= x0;
  x0 += k1; x1 += ks2 + 1u;
  x0 += x1; x1 = TF_ROT(x1, 17); x1 ^= x0;
  x0 += x1; x1 = TF_ROT(x1, 29); x1 ^= x0;
  x0 += x1; x1 = TF_ROT(x1, 16); x1 ^= x0;
  x0 += x1; x1 = TF_ROT(x1, 24); x1 ^= x0;
  x0 += ks2; x1 += k0 + 2u;
  x0 += x1; x1 = TF_ROT(x1, 13); x1 ^= x0;
  x0 += x1; x1 = TF_ROT(x1, 15); x1 ^= x0;
  x0 += x1; x1 = TF_ROT(x1, 26); x1 ^= x0;
  x0 += x1; x1 = TF_ROT(x1, 6);  x1 ^= x0;
  x0 += k0; x1 += k1 + 3u;
  x0 += x1; x1 = TF_ROT(x1, 17); x1 ^= x0;
  x0 += x1; x1 = TF_ROT(x1, 29); x1 ^= x0;
  x0 += x1; x1 = TF_ROT(x1, 16); x1 ^= x0;
  x0 += x1; x1 = TF_ROT(x1, 24); x1 ^= x0;
  x0 += k1; x1 += ks2 + 4u;
  x0 += x1; x1 = TF_ROT(x1, 13); x1 ^= x0;
  x0 += x1; x1 = TF_ROT(x1, 15); x1 ^= x0;
  x0 += x1; x1 = TF_ROT(x1, 26); x1 ^= x0;
  x0 += x1; x1 = TF_ROT(x1, 6);  x1 ^= x0;
  x0 += ks2; x1 += k0 + 5u;
  *o0 = x0; *o1 = x1;
}

// ---------------- numeric helpers (match XLA/JAX) ----------------
__device__ static inline float bits_to_u01(uint32_t b) {
  uint32_t f = (b >> 9) | 0x3f800000u;
  return __uint_as_float(f) - 1.0f;          // [0, 1)
}
__device__ static inline float unif_f(uint32_t b, float lo, float hi) {
  float f = bits_to_u01(b);
  return fmaxf(lo, f * (hi - lo) + lo);
}
// XLA ErfInv (f32, Giles polynomial)
__device__ static inline float erfinv_f(float x) {
  float w = -log1pf(-x * x);
  float p;
  if (w < 5.f) {
    w -= 2.5f;
    p = 2.81022636e-08f;
    p = fmaf(p, w, 3.43273939e-07f);
    p = fmaf(p, w, -3.5233877e-06f);
    p = fmaf(p, w, -4.39150654e-06f);
    p = fmaf(p, w, 0.00021858087f);
    p = fmaf(p, w, -0.00125372503f);
    p = fmaf(p, w, -0.00417768164f);
    p = fmaf(p, w, 0.246640727f);
    p = fmaf(p, w, 1.50140941f);
  } else {
    w = sqrtf(w) - 3.f;
    p = -0.000200214257f;
    p = fmaf(p, w, 0.000100950558f);
    p = fmaf(p, w, 0.00134934322f);
    p = fmaf(p, w, -0.00367342844f);
    p = fmaf(p, w, 0.00573950773f);
    p = fmaf(p, w, -0.0076224613f);
    p = fmaf(p, w, 0.00943887047f);
    p = fmaf(p, w, 1.00167406f);
    p = fmaf(p, w, 2.83297682f);
  }
  return p * x;
}
__device__ static inline float softplus_f(float x) {
  return fmaxf(x, 0.f) + log1pf(expf(-fabsf(x)));
}
__device__ static inline float sigmoid_f(float x) {
  return 1.f / (1.f + expf(-x));
}
__device__ static inline float digamma_f(float x) {
  float r = 0.f;
  while (x < 6.f) { r -= 1.f / x; x += 1.f; }
  float inv = 1.f / x, inv2 = inv * inv;
  return r + logf(x) - 0.5f * inv
       - inv2 * (1.f / 12.f - inv2 * (1.f / 120.f - inv2 * (1.f / 252.f)));
}

// block-wide sum; valid result only on thread 0
__device__ static inline float block_sum(float v) {
  __shared__ float sm[16];
  int lane = threadIdx.x & 63;
  int wid = threadIdx.x >> 6;
  #pragma unroll
  for (int o = 32; o > 0; o >>= 1) v += __shfl_down(v, o, 64);
  if (lane == 0) sm[wid] = v;
  __syncthreads();
  float s = 0.f;
  if (threadIdx.x == 0) {
    int nw = (blockDim.x + 63) >> 6;
    s = sm[0];
    for (int w = 1; w < nw; ++w) s += sm[w];
  }
  return s;
}

// ---------------- kernels ----------------
__global__ void k_init(float* acc) {
  if (threadIdx.x < 8) acc[threadIdx.x] = 0.f;
}

// z_sample (relaxed Bernoulli of t_pi) and Kumaraswamy q_u; each thread does
// one threefry pair per stream -> elements (i, i+HU)
__global__ __launch_bounds__(256) void k_zqu(const float* __restrict__ t_pi,
                                             const float* __restrict__ conc1,
                                             const float* __restrict__ conc0,
                                             float* __restrict__ z,
                                             float* __restrict__ qu,
                                             uint32_t uk0, uint32_t uk1,
                                             uint32_t qk0, uint32_t qk1) {
  int i = blockIdx.x * blockDim.x + threadIdx.x;
  if (i >= HU) return;
  uint32_t a0, a1, b0, b1;
  threefry2x32(uk0, uk1, (uint32_t)i, (uint32_t)(i + HU), &a0, &a1);
  threefry2x32(qk0, qk1, (uint32_t)i, (uint32_t)(i + HU), &b0, &b1);
  const float lo = 1e-6f, hi = 1.f - 1e-6f;
  #pragma unroll
  for (int h = 0; h < 2; ++h) {
    int n = i + h * HU;
    uint32_t ub = h ? a1 : a0;
    uint32_t qb = h ? b1 : b0;
    float u = unif_f(ub, lo, hi);
    float logistic = logf(u) - log1pf(-u);
    z[n] = sigmoid_f((t_pi[n] + logistic) / TEMP);
    int k = n & (K_N - 1);
    float a_sp = softplus_f(conc1[k]);
    float b_sp = softplus_f(conc0[k]);
    float ukv = unif_f(qb, lo, hi);
    qu[n] = powf(1.f - powf(ukv, 1.f / b_sp), 1.f / a_sp);
  }
}

// kl_z (cumprod prior along d, f32 sequential to match underflow) + kl_sticks
__global__ void k_klz(const float* __restrict__ t_pi,
                      const float* __restrict__ qu,
                      const float* __restrict__ conc1,
                      const float* __restrict__ conc0,
                      float* acc) {
  int k = threadIdx.x;  // one block of 512
  float prior = 1.f, s = 0.f;
  for (int d = 0; d < D_N; ++d) {
    int n = d * K_N + k;
    prior *= qu[n];
    float q = sigmoid_f(t_pi[n]);
    s += q * (logf(q + EPS_F) - logf(prior + EPS_F));
  }
  float a = softplus_f(conc1[k]);
  float b = softplus_f(conc0[k]);
  s += ((a - 1.f) / a) * (-EULERC - digamma_f(b) - 1.f / b)
     + logf(a * b + EPS_F) - (b - 1.f) / b;
  float t = block_sum(s);
  if (threadIdx.x == 0) atomicAdd(&acc[1], t);
}

// W = z * (mW + eps*softplus(sW)); also kl_weights partial sums
__global__ __launch_bounds__(256) void k_wbuild(const float* __restrict__ mW,
                                                const float* __restrict__ sW,
                                                const float* __restrict__ z,
                                                float* __restrict__ Wz,
                                                float* acc,
                                                uint32_t ek0, uint32_t ek1) {
  int i = blockIdx.x * blockDim.x + threadIdx.x;
  uint32_t b0, b1;
  threefry2x32(ek0, ek1, (uint32_t)i, (uint32_t)(i + HEPS), &b0, &b1);
  const float lo = -0.99999994f, hi = 1.0f;
  float klw = 0.f;
  #pragma unroll
  for (int h = 0; h < 2; ++h) {
    int n = i + h * HEPS;
    uint32_t bits = h ? b1 : b0;
    float u = unif_f(bits, lo, hi);
    float epsn = 1.41421356f * erfinv_f(u);   // sqrt(2) in f32
    float m = mW[n];
    float sp = softplus_f(sW[n]);
    float W = m + epsn * sp;
    int d = n >> 10, j = n & (KU_N - 1);
    float zz = z[(d << 9) + (j & (K_N - 1))];
    Wz[n] = zz * W;
    klw += 2.f * sp - m * m - sp * sp + 1.f;
  }
  float t = block_sum(klw);
  if (threadIdx.x == 0) atomicAdd(&acc[0], t);
}

// fp32 tiled GEMM: C[b, j] = sum_d A[b, d] * Wz[d, j] + bias[j]
#define BM 64
#define BN 64
#define BK 16
__global__ __launch_bounds__(256) void k_gemm(const float* __restrict__ A,
                                              const float* __restrict__ Bm,
                                              const float* __restrict__ bias,
                                              float* __restrict__ C) {
  __shared__ float As[BK][BM];
  __shared__ float Bs[BK][BN];
  const int bx = blockIdx.x;           // N tile: 0..15
  const int by = blockIdx.y;           // M tile: 0..255
  const int tid = threadIdx.x;
  const int tx = tid & 15;             // 0..15 (col group)
  const int ty = tid >> 4;             // 0..15 (row group)
  const int rowA = tid >> 2;           // 0..63
  const int colA = (tid & 3) << 2;     // 0,4,8,12
  const int rowB = tid >> 4;           // 0..15
  const int colB = (tid & 15) << 2;    // 0..60

  float acc[4][4];
  #pragma unroll
  for (int i = 0; i < 4; ++i)
    #pragma unroll
    for (int j = 0; j < 4; ++j) acc[i][j] = 0.f;

  const int arow = by * BM + rowA;
  const int bcol = bx * BN;

  for (int kt = 0; kt < D_N; kt += BK) {
    float4 av = *(const float4*)&A[arow * D_N + kt + colA];
    As[colA + 0][rowA] = av.x;
    As[colA + 1][rowA] = av.y;
    As[colA + 2][rowA] = av.z;
    As[colA + 3][rowA] = av.w;
    float4 bv = *(const float4*)&Bm[(kt + rowB) * KU_N + bcol + colB];
    *(float4*)&Bs[rowB][colB] = bv;
    __syncthreads();
    #pragma unroll
    for (int kk = 0; kk < BK; ++kk) {
      float4 a = *(float4*)&As[kk][ty << 2];
      float4 b = *(float4*)&Bs[kk][tx << 2];
      acc[0][0] = fmaf(a.x, b.x, acc[0][0]);
      acc[0][1] = fmaf(a.x, b.y, acc[0][1]);
      acc[0][2] = fmaf(a.x, b.z, acc[0][2]);
      acc[0][3] = fmaf(a.x, b.w, acc[0][3]);
      acc[1][0] = fmaf(a.y, b.x, acc[1][0]);
      acc[1][1] = fmaf(a.y, b.y, acc[1][1]);
      acc[1][2] = fmaf(a.y, b.z, acc[1][2]);
      acc[1][3] = fmaf(a.y, b.w, acc[1][3]);
      acc[2][0] = fmaf(a.z, b.x, acc[2][0]);
      acc[2][1] = fmaf(a.z, b.y, acc[2][1]);
      acc[2][2] = fmaf(a.z, b.z, acc[2][2]);
      acc[2][3] = fmaf(a.z, b.w, acc[2][3]);
      acc[3][0] = fmaf(a.w, b.x, acc[3][0]);
      acc[3][1] = fmaf(a.w, b.y, acc[3][1]);
      acc[3][2] = fmaf(a.w, b.z, acc[3][2]);
      acc[3][3] = fmaf(a.w, b.w, acc[3][3]);
    }
    __syncthreads();
  }

  const int cbase = bcol + (tx << 2);
  float4 biasv = *(const float4*)&bias[cbase];
  #pragma unroll
  for (int i = 0; i < 4; ++i) {
    int r = by * BM + (ty << 2) + i;
    float4 st;
    st.x = acc[i][0] + biasv.x;
    st.y = acc[i][1] + biasv.y;
    st.z = acc[i][2] + biasv.z;
    st.w = acc[i][3] + biasv.w;
    *(float4*)&C[r * KU_N + cbase] = st;
  }
}

// LWTA epilogue: Gumbel-softmax over U=2, in place on C; kl_xi partials.
// Thread (b, k) with b<8192 handles rows b and b+8192 so both threefry
// outputs of pair (m, m+HG) are consumed.
__device__ static inline float lwta_row(float* C, int row, int k,
                                        uint32_t g0b, uint32_t g1b) {
  const float lo = 1e-6f, hi = 1.f - 1e-6f;
  int base = row * KU_N + (k << 1);
  float2 l = *(float2*)&C[base];
  float u0 = unif_f(g0b, lo, hi);
  float u1 = unif_f(g1b, lo, hi);
  float g0 = -logf(-logf(u0));
  float g1 = -logf(-logf(u1));
  float s0 = (l.x + g0) / TEMP;
  float s1 = (l.y + g1) / TEMP;
  float mx = fmaxf(s0, s1);
  float e0 = expf(s0 - mx), e1 = expf(s1 - mx);
  float inv = 1.f / (e0 + e1);
  float2 o;
  o.x = l.x * (e0 * inv);
  o.y = l.y * (e1 * inv);
  *(float2*)&C[base] = o;
  // q_xi = softmax(logits) (no temperature)
  float qmx = fmaxf(l.x, l.y);
  float f0 = expf(l.x - qmx), f1 = expf(l.y - qmx);
  float qinv = 1.f / (f0 + f1);
  float q0 = f0 * qinv, q1 = f1 * qinv;
  const float LOG_HALF = -0.6931471805599453f;
  return q0 * (logf(q0 + EPS_F) - LOG_HALF) + q1 * (logf(q1 + EPS_F) - LOG_HALF);
}

__global__ __launch_bounds__(256) void k_epi(float* __restrict__ C,
                                             float* __restrict__ partial,
                                             uint32_t gk0, uint32_t gk1) {
  int idx = blockIdx.x * blockDim.x + threadIdx.x;  // [0, 8192*512)
  int b = idx >> 9;
  int k = idx & (K_N - 1);
  uint32_t m = (uint32_t)b * KU_N + ((uint32_t)k << 1);
  uint32_t p0a, p0b, p1a, p1b;
  threefry2x32(gk0, gk1, m, m + HG, &p0a, &p0b);
  threefry2x32(gk0, gk1, m + 1u, m + 1u + HG, &p1a, &p1b);
  float kl = lwta_row(C, b, k, p0a, p1a) + lwta_row(C, b + 8192, k, p0b, p1b);
  float t = block_sum(kl);
  if (threadIdx.x == 0) partial[blockIdx.x] = t;
}

__global__ void k_final(const float* __restrict__ acc,
                        const float* __restrict__ partial, int npart,
                        float* __restrict__ out_loss) {
  float s = 0.f;
  for (int i = threadIdx.x; i < npart; i += blockDim.x) s += partial[i];
  float t = block_sum(s);
  if (threadIdx.x == 0) {
    float kl_weights = -0.5f * (acc[0] / 1048576.f);
    float loss = kl_weights / 60000.f + acc[1] + t / 32768.f;
    out_loss[0] = loss;
  }
}

// ---------------- launch ----------------
extern "C" void kernel_launch(void* const* d_in, const int* in_sizes, int n_in,
                              void* d_out, int out_size, void* d_ws, size_t ws_size,
                              hipStream_t stream) {
  (void)in_sizes; (void)n_in; (void)out_size; (void)ws_size;
  const float* inputs = (const float*)d_in[0];
  const float* mW     = (const float*)d_in[1];
  const float* sW     = (const float*)d_in[2];
  const float* conc1  = (const float*)d_in[3];
  const float* conc0  = (const float*)d_in[4];
  const float* t_pi   = (const float*)d_in[5];
  const float* biases = (const float*)d_in[6];
  float* out = (float*)d_out;

  // derive rk[0..3] = split(key(42), 4) on host (JAX threefry_split)
  uint32_t a[4], b[4];
  for (int i = 0; i < 4; ++i)
    threefry2x32(0u, 42u, (uint32_t)i, (uint32_t)(i + 4), &a[i], &b[i]);
  // rk0=(a0,a1) rk1=(a2,a3) rk2=(b0,b1) rk3=(b2,b3)
  uint32_t e_k0 = a[0], e_k1 = a[1];   // eps (normal) key
  uint32_t u_k0 = a[2], u_k1 = a[3];   // bernoulli-u key
  uint32_t q_k0 = b[0], q_k1 = b[1];   // kumaraswamy key
  uint32_t g_k0 = b[2], g_k1 = b[3];   // gumbel key

  float* ws = (float*)d_ws;
  float* Wz      = ws;                  // 1048576
  float* z       = ws + 1048576;        // 524288
  float* qu      = ws + 1572864;        // 524288
  float* acc     = ws + 2097152;        // 8
  float* partial = ws + 2097160;        // 16384

  hipLaunchKernelGGL(k_init, dim3(1), dim3(64), 0, stream, acc);
  hipLaunchKernelGGL(k_zqu, dim3(HU / 256), dim3(256), 0, stream,
                     t_pi, conc1, conc0, z, qu, u_k0, u_k1, q_k0, q_k1);
  hipLaunchKernelGGL(k_klz, dim3(1), dim3(512), 0, stream,
                     t_pi, qu, conc1, conc0, acc);
  hipLaunchKernelGGL(k_wbuild, dim3(HEPS / 256), dim3(256), 0, stream,
                     mW, sW, z, Wz, acc, e_k0, e_k1);
  hipLaunchKernelGGL(k_gemm, dim3(KU_N / BN, B_N / BM), dim3(256), 0, stream,
                     inputs, Wz, biases, out);
  hipLaunchKernelGGL(k_epi, dim3(8192 * 512 / 256), dim3(256), 0, stream,
                     out, partial, g_k0, g_k1);
  hipLaunchKernelGGL(k_final, dim3(1), dim3(256), 0, stream,
                     acc, partial, 16384, out + 16777216);
}

// Round 2
// 213.181 us; speedup vs baseline: 3.7327x; 3.7327x over previous
//
#include <hip/hip_runtime.h>
#include <stdint.h>
#include <math.h>

// ---------------- problem constants ----------------
#define B_N   16384
#define D_N   1024
#define K_N   512
#define KU_N  1024          // K*U
#define EPS_F 1e-8f
#define TEMP  0.67f
#define EULERC 0.5772156649015329f

#define HEPS  524288        // 2^19  (eps stream half)
#define HU    262144        // 2^18  (bernoulli/kumaraswamy stream half)
#define HG    8388608       // 2^23  (gumbel stream half)

typedef uint32_t u32;
typedef __attribute__((ext_vector_type(4))) float f32x4;
typedef __attribute__((ext_vector_type(8))) __bf16 bf16x8;

// ---------------- threefry2x32 (JAX-exact) ----------------
#define TF_ROT(x, r) (((x) << (r)) | ((x) >> (32 - (r))))

__host__ __device__ static inline void threefry2x32(u32 k0, u32 k1,
                                                    u32 x0, u32 x1,
                                                    u32* o0, u32* o1) {
  u32 ks2 = k0 ^ k1 ^ 0x1BD11BDAu;
  x0 += k0; x1 += k1;
  x0 += x1; x1 = TF_ROT(x1, 13); x1 ^= x0;
  x0 += x1; x1 = TF_ROT(x1, 15); x1 ^= x0;
  x0 += x1; x1 = TF_ROT(x1, 26); x1 ^= x0;
  x0 += x1; x1 = TF_ROT(x1, 6);  x1 ^= x0;
  x0 += k1; x1 += ks2 + 1u;
  x0 += x1; x1 = TF_ROT(x1, 17); x1 ^= x0;
  x0 += x1; x1 = TF_ROT(x1, 29); x1 ^= x0;
  x0 += x1; x1 = TF_ROT(x1, 16); x1 ^= x0;
  x0 += x1; x1 = TF_ROT(x1, 24); x1 ^= x0;
  x0 += ks2; x1 += k0 + 2u;
  x0 += x1; x1 = TF_ROT(x1, 13); x1 ^= x0;
  x0 += x1; x1 = TF_ROT(x1, 15); x1 ^= x0;
  x0 += x1; x1 = TF_ROT(x1, 26); x1 ^= x0;
  x0 += x1; x1 = TF_ROT(x1, 6);  x1 ^= x0;
  x0 += k0; x1 += k1 + 3u;
  x0 += x1; x1 = TF_ROT(x1, 17); x1 ^= x0;
  x0 += x1; x1 = TF_ROT(x1, 29); x1 ^= x0;
  x0 += x1; x1 = TF_ROT(x1, 16); x1 ^= x0;
  x0 += x1; x1 = TF_ROT(x1, 24); x1 ^= x0;
  x0 += k1; x1 += ks2 + 4u;
  x0 += x1; x1 = TF_ROT(x1, 13); x1 ^= x0;
  x0 += x1; x1 = TF_ROT(x1, 15); x1 ^= x0;
  x0 += x1; x1 = TF_ROT(x1, 26); x1 ^= x0;
  x0 += x1; x1 = TF_ROT(x1, 6);  x1 ^= x0;
  x0 += ks2; x1 += k0 + 5u;
  *o0 = x0; *o1 = x1;
}

// ---------------- numeric helpers ----------------
__device__ static inline float bits_to_u01(u32 b) {
  u32 f = (b >> 9) | 0x3f800000u;
  return __uint_as_float(f) - 1.0f;
}
__device__ static inline float unif_f(u32 b, float lo, float hi) {
  float f = bits_to_u01(b);
  return fmaxf(lo, f * (hi - lo) + lo);
}
__device__ static inline float erfinv_f(float x) {
  float w = -log1pf(-x * x);
  float p;
  if (w < 5.f) {
    w -= 2.5f;
    p = 2.81022636e-08f;
    p = fmaf(p, w, 3.43273939e-07f);
    p = fmaf(p, w, -3.5233877e-06f);
    p = fmaf(p, w, -4.39150654e-06f);
    p = fmaf(p, w, 0.00021858087f);
    p = fmaf(p, w, -0.00125372503f);
    p = fmaf(p, w, -0.00417768164f);
    p = fmaf(p, w, 0.246640727f);
    p = fmaf(p, w, 1.50140941f);
  } else {
    w = sqrtf(w) - 3.f;
    p = -0.000200214257f;
    p = fmaf(p, w, 0.000100950558f);
    p = fmaf(p, w, 0.00134934322f);
    p = fmaf(p, w, -0.00367342844f);
    p = fmaf(p, w, 0.00573950773f);
    p = fmaf(p, w, -0.0076224613f);
    p = fmaf(p, w, 0.00943887047f);
    p = fmaf(p, w, 1.00167406f);
    p = fmaf(p, w, 2.83297682f);
  }
  return p * x;
}
__device__ static inline float softplus_f(float x) {
  return fmaxf(x, 0.f) + log1pf(expf(-fabsf(x)));
}
__device__ static inline float rcp_f(float x) { return __builtin_amdgcn_rcpf(x); }
__device__ static inline float sigmoid_fast(float x) {
  return rcp_f(1.f + __expf(-x));
}
__device__ static inline float digamma_f(float x) {
  float r = 0.f;
  while (x < 6.f) { r -= 1.f / x; x += 1.f; }
  float inv = 1.f / x, inv2 = inv * inv;
  return r + logf(x) - 0.5f * inv
       - inv2 * (1.f / 12.f - inv2 * (1.f / 120.f - inv2 * (1.f / 252.f)));
}
__device__ static inline unsigned short f2bf_rne(float x) {
  u32 u = __float_as_uint(x);
  u32 r = (u + 0x7fffu + ((u >> 16) & 1u)) >> 16;
  return (unsigned short)r;
}
__device__ static inline u32 cvt_pk_bf16(float lo, float hi) {
  u32 r;
  asm("v_cvt_pk_bf16_f32 %0, %1, %2" : "=v"(r) : "v"(lo), "v"(hi));
  return r;
}
__device__ static inline void gload_lds16(const void* g, void* l) {
  __builtin_amdgcn_global_load_lds(
      (const __attribute__((address_space(1))) u32*)g,
      (__attribute__((address_space(3))) u32*)l, 16, 0, 0);
}

// block-wide sum; valid result only on thread 0
__device__ static inline float block_sum(float v) {
  __shared__ float sm[16];
  int lane = threadIdx.x & 63;
  int wid = threadIdx.x >> 6;
  #pragma unroll
  for (int o = 32; o > 0; o >>= 1) v += __shfl_down(v, o, 64);
  if (lane == 0) sm[wid] = v;
  __syncthreads();
  float s = 0.f;
  if (threadIdx.x == 0) {
    int nw = (blockDim.x + 63) >> 6;
    s = sm[0];
    for (int w = 1; w < nw; ++w) s += sm[w];
  }
  return s;
}

// ---------------- kernels ----------------
// init: zero acc, per-k tables (1/a_sp, 1/b_sp), kl_sticks -> acc[1]
__global__ void k_init(const float* __restrict__ conc1,
                       const float* __restrict__ conc0,
                       float* __restrict__ invA, float* __restrict__ invB,
                       float* acc) {
  int k = threadIdx.x;  // 512
  float a = softplus_f(conc1[k]);
  float b = softplus_f(conc0[k]);
  invA[k] = 1.f / a;
  invB[k] = 1.f / b;
  float s = ((a - 1.f) / a) * (-EULERC - digamma_f(b) - 1.f / b)
          + logf(a * b + EPS_F) - (b - 1.f) / b;
  float t = block_sum(s);
  if (threadIdx.x == 0) { acc[0] = 0.f; acc[1] = t; }
}

// Kumaraswamy q_u samples
__global__ __launch_bounds__(256) void k_qu(const float* __restrict__ invA,
                                            const float* __restrict__ invB,
                                            float* __restrict__ qu,
                                            u32 qk0, u32 qk1) {
  int i = blockIdx.x * 256 + threadIdx.x;   // < HU
  u32 b0, b1;
  threefry2x32(qk0, qk1, (u32)i, (u32)(i + HU), &b0, &b1);
  const float lo = 1e-6f, hi = 1.f - 1e-6f;
  #pragma unroll
  for (int h = 0; h < 2; ++h) {
    int n = i + h * HU;
    u32 qb = h ? b1 : b0;
    int k = n & (K_N - 1);
    float u = unif_f(qb, lo, hi);
    qu[n] = powf(1.f - powf(u, invB[k]), invA[k]);
  }
}

// kl_z pass A: per-chunk products (8 chunks of 128 d's, per column k)
__global__ __launch_bounds__(256) void k_klz_a(const float* __restrict__ qu,
                                               float* __restrict__ P) {
  int idx = blockIdx.x * 256 + threadIdx.x;  // [0, 4096)
  int c = idx >> 9, k = idx & (K_N - 1);
  float p = 1.f;
  int d0 = c * 128;
  #pragma unroll 8
  for (int d = d0; d < d0 + 128; ++d) p *= qu[d * K_N + k];
  P[c * K_N + k] = p;
}

// kl_z pass B: prefix-recombined cumprod + KL sum -> atomicAdd acc[1]
__global__ __launch_bounds__(256) void k_klz_b(const float* __restrict__ t_pi,
                                               const float* __restrict__ qu,
                                               const float* __restrict__ P,
                                               float* acc) {
  int idx = blockIdx.x * 256 + threadIdx.x;  // [0, 4096)
  int c = idx >> 9, k = idx & (K_N - 1);
  float prior = 1.f;
  for (int c2 = 0; c2 < c; ++c2) prior *= P[c2 * K_N + k];
  float s = 0.f;
  int d0 = c * 128;
  #pragma unroll 4
  for (int d = d0; d < d0 + 128; ++d) {
    int n = d * K_N + k;
    prior *= qu[n];
    float q = sigmoid_fast(t_pi[n]);
    s += q * (__logf(q + EPS_F) - __logf(prior + EPS_F));
  }
  float t = block_sum(s);
  if (threadIdx.x == 0) atomicAdd(&acc[1], t);
}

// WzT[j][d] = z(d, j%K) * (mW[d][j] + eps*softplus(sW[d][j]))  (bf16),
// z computed inline; kl_weights partials -> acc[0]
__global__ __launch_bounds__(256) void k_wbuildT(const float* __restrict__ mW,
                                                 const float* __restrict__ sW,
                                                 const float* __restrict__ t_pi,
                                                 unsigned short* __restrict__ WzT,
                                                 float* acc,
                                                 u32 ek0, u32 ek1,
                                                 u32 uk0, u32 uk1) {
  int idx = blockIdx.x * 256 + threadIdx.x;  // [0, 2^19)
  int j = idx >> 9;            // output col 0..1023
  int dlo = idx & 511;         // 0..511
  int kk = j & (K_N - 1);

  int n0 = dlo * KU_N + j;     // < 2^19
  u32 e0, e1;
  threefry2x32(ek0, ek1, (u32)n0, (u32)(n0 + HEPS), &e0, &e1);
  int nz0 = dlo * K_N + kk;    // < 2^18
  u32 z0b, z1b;
  threefry2x32(uk0, uk1, (u32)nz0, (u32)(nz0 + HU), &z0b, &z1b);

  const float lo = 1e-6f, hi = 1.f - 1e-6f;
  const float nlo = -0.99999994f, nhi = 1.0f;
  float klw = 0.f;
  {
    float u = unif_f(z0b, lo, hi);
    float logistic = __logf(u) - log1pf(-u);
    float z = sigmoid_fast((t_pi[nz0] + logistic) * (1.f / TEMP));
    float un = unif_f(e0, nlo, nhi);
    float epsn = 1.41421356f * erfinv_f(un);
    float m = mW[n0], sp = softplus_f(sW[n0]);
    float W = m + epsn * sp;
    WzT[j * D_N + dlo] = f2bf_rne(z * W);
    klw += 2.f * sp - m * m - sp * sp + 1.f;
  }
  {
    int n1 = n0 + HEPS;        // d = dlo+512
    int nz1 = nz0 + HU;
    float u = unif_f(z1b, lo, hi);
    float logistic = __logf(u) - log1pf(-u);
    float z = sigmoid_fast((t_pi[nz1] + logistic) * (1.f / TEMP));
    float un = unif_f(e1, nlo, nhi);
    float epsn = 1.41421356f * erfinv_f(un);
    float m = mW[n1], sp = softplus_f(sW[n1]);
    float W = m + epsn * sp;
    WzT[j * D_N + dlo + 512] = f2bf_rne(z * W);
    klw += 2.f * sp - m * m - sp * sp + 1.f;
  }
  float t = block_sum(klw);
  if (threadIdx.x == 0) atomicAdd(&acc[0], t);
}

// ---------------- MFMA GEMM: C[b][j] = sum_d A[b][d]*WzT[j][d] + bias[j] ----
#define GBM 128
#define GBN 128
#define GBK 32

__global__ __launch_bounds__(256) void k_gemm(const float* __restrict__ A,
                                              const unsigned short* __restrict__ Bt,
                                              const float* __restrict__ bias,
                                              float* __restrict__ C) {
  __shared__ float As[GBM * GBK];            // 16KB, [row][32] f32, 16B-slot XOR swizzle
  __shared__ unsigned short Bs[GBN * GBK];   // 8KB,  [col][32] bf16, slot XOR swizzle

  const int tid = threadIdx.x;
  const int lane = tid & 63;
  const int w = tid >> 6;
  const int brow = blockIdx.y * GBM;
  const int bcol = blockIdx.x * GBN;

  // A staging: issue q covers rows q*32..q*32+31; thread t -> row q*32+(t>>3),
  // 16B slot t&7; pre-swizzled global chunk c = (t&7) ^ ((t>>3)&7)
  const int arr = tid >> 3;
  const int aco = ((tid & 7) ^ (arr & 7)) << 2;       // float col offset
  const float* gA = A + (brow + arr) * D_N + aco;
  // B staging: issue q covers cols q*64..; row q*64+(t>>2), slot t&3,
  // global chunk c = (t&3) ^ ((t>>2)&3)
  const int brr = tid >> 2;
  const int bco = ((tid & 3) ^ (brr & 3)) << 3;       // bf16 col offset
  const unsigned short* gB = Bt + (bcol + brr) * D_N + bco;

  f32x4 acc[4][4];
  #pragma unroll
  for (int m = 0; m < 4; ++m)
    #pragma unroll
    for (int n = 0; n < 4; ++n) acc[m][n] = (f32x4){0.f, 0.f, 0.f, 0.f};

  const int wr = (w >> 1) << 6;   // 0 or 64
  const int wc = (w & 1) << 6;    // 0 or 64
  const int fr = lane & 15;
  const int kg = lane >> 4;       // 0..3

  union BF8 { u32 u[4]; bf16x8 v; };

  for (int kt = 0; kt < D_N; kt += GBK) {
    #pragma unroll
    for (int q = 0; q < 4; ++q)
      gload_lds16(gA + q * (32 * D_N) + kt, (char*)As + q * 4096 + (w << 10));
    #pragma unroll
    for (int q = 0; q < 2; ++q)
      gload_lds16(gB + q * (64 * D_N) + kt, (char*)Bs + q * 4096 + (w << 10));
    __syncthreads();

    BF8 af[4];
    #pragma unroll
    for (int m = 0; m < 4; ++m) {
      int row = wr + m * 16 + fr;
      int r7 = row & 7;
      const float* pa = As + row * GBK;
      f32x4 lov = *(const f32x4*)(pa + ((((kg << 1)    ) ^ r7) << 2));
      f32x4 hiv = *(const f32x4*)(pa + ((((kg << 1) | 1) ^ r7) << 2));
      af[m].u[0] = cvt_pk_bf16(lov.x, lov.y);
      af[m].u[1] = cvt_pk_bf16(lov.z, lov.w);
      af[m].u[2] = cvt_pk_bf16(hiv.x, hiv.y);
      af[m].u[3] = cvt_pk_bf16(hiv.z, hiv.w);
    }
    #pragma unroll
    for (int n = 0; n < 4; ++n) {
      int col = wc + n * 16 + fr;
      bf16x8 bf = *(const bf16x8*)(Bs + col * GBK + ((kg ^ (col & 3)) << 3));
      #pragma unroll
      for (int m = 0; m < 4; ++m)
        acc[m][n] = __builtin_amdgcn_mfma_f32_16x16x32_bf16(af[m].v, bf, acc[m][n], 0, 0, 0);
    }
    __syncthreads();
  }

  #pragma unroll
  for (int n = 0; n < 4; ++n) {
    int col = bcol + wc + n * 16 + fr;
    float bv = bias[col];
    #pragma unroll
    for (int m = 0; m < 4; ++m) {
      int rowb = brow + wr + m * 16 + (kg << 2);
      C[(rowb + 0) * KU_N + col] = acc[m][n].x + bv;
      C[(rowb + 1) * KU_N + col] = acc[m][n].y + bv;
      C[(rowb + 2) * KU_N + col] = acc[m][n].z + bv;
      C[(rowb + 3) * KU_N + col] = acc[m][n].w + bv;
    }
  }
}

// ---------------- LWTA epilogue ----------------
__device__ static inline float lwta_row(float* C, int row, int k,
                                        u32 g0b, u32 g1b) {
  const float lo = 1e-6f, hi = 1.f - 1e-6f;
  int base = row * KU_N + (k << 1);
  float2 l = *(float2*)&C[base];
  float u0 = unif_f(g0b, lo, hi);
  float u1 = unif_f(g1b, lo, hi);
  float g0 = -__logf(-__logf(u0));
  float g1 = -__logf(-__logf(u1));
  const float it = 1.f / TEMP;
  float d = (l.y + g1) * it - (l.x + g0) * it;
  float xi0 = rcp_f(1.f + __expf(d));     // softmax pair
  float xi1 = 1.f - xi0;
  float2 o;
  o.x = l.x * xi0;
  o.y = l.y * xi1;
  *(float2*)&C[base] = o;
  float qd = l.y - l.x;
  float q0 = rcp_f(1.f + __expf(qd));
  float q1 = 1.f - q0;
  const float LOG_HALF = -0.6931471805599453f;
  return q0 * (__logf(q0 + EPS_F) - LOG_HALF) + q1 * (__logf(q1 + EPS_F) - LOG_HALF);
}

__global__ __launch_bounds__(256) void k_epi(float* __restrict__ C,
                                             float* __restrict__ partial,
                                             u32 gk0, u32 gk1) {
  int idx = blockIdx.x * 256 + threadIdx.x;  // [0, 8192*512)
  int b = idx >> 9;
  int k = idx & (K_N - 1);
  u32 m = ((u32)b << 10) + ((u32)k << 1);
  u32 p0a, p0b, p1a, p1b;
  threefry2x32(gk0, gk1, m, m + HG, &p0a, &p0b);
  threefry2x32(gk0, gk1, m + 1u, m + 1u + HG, &p1a, &p1b);
  float kl = lwta_row(C, b, k, p0a, p1a) + lwta_row(C, b + 8192, k, p0b, p1b);
  float t = block_sum(kl);
  if (threadIdx.x == 0) partial[blockIdx.x] = t;
}

__global__ void k_final(const float* __restrict__ acc,
                        const float* __restrict__ partial, int npart,
                        float* __restrict__ out_loss) {
  float s = 0.f;
  for (int i = threadIdx.x; i < npart; i += blockDim.x) s += partial[i];
  float t = block_sum(s);
  if (threadIdx.x == 0) {
    float kl_weights = -0.5f * (acc[0] / 1048576.f);
    out_loss[0] = kl_weights / 60000.f + acc[1] + t / 32768.f;
  }
}

// ---------------- launch ----------------
extern "C" void kernel_launch(void* const* d_in, const int* in_sizes, int n_in,
                              void* d_out, int out_size, void* d_ws, size_t ws_size,
                              hipStream_t stream) {
  (void)in_sizes; (void)n_in; (void)out_size; (void)ws_size;
  const float* inputs = (const float*)d_in[0];
  const float* mW     = (const float*)d_in[1];
  const float* sW     = (const float*)d_in[2];
  const float* conc1  = (const float*)d_in[3];
  const float* conc0  = (const float*)d_in[4];
  const float* t_pi   = (const float*)d_in[5];
  const float* biases = (const float*)d_in[6];
  float* out = (float*)d_out;

  // rk[0..3] = split(key(42), 4)
  u32 a[4], b[4];
  for (int i = 0; i < 4; ++i)
    threefry2x32(0u, 42u, (u32)i, (u32)(i + 4), &a[i], &b[i]);
  u32 e_k0 = a[0], e_k1 = a[1];   // eps (normal)
  u32 u_k0 = a[2], u_k1 = a[3];   // bernoulli-u
  u32 q_k0 = b[0], q_k1 = b[1];   // kumaraswamy
  u32 g_k0 = b[2], g_k1 = b[3];   // gumbel

  char* wsb = (char*)d_ws;
  unsigned short* WzT = (unsigned short*)wsb;                   // 2MB
  float* qu      = (float*)(wsb + (2u << 20));                  // 2MB
  float* Pch     = (float*)(wsb + (4u << 20));                  // 16KB
  float* invA    = (float*)(wsb + (4u << 20) + (16u << 10));    // 2KB
  float* invB    = (float*)(wsb + (4u << 20) + (18u << 10));    // 2KB
  float* acc     = (float*)(wsb + (4u << 20) + (20u << 10));    // 32B
  float* partial = (float*)(wsb + (4u << 20) + (24u << 10));    // 64KB

  hipLaunchKernelGGL(k_init, dim3(1), dim3(512), 0, stream,
                     conc1, conc0, invA, invB, acc);
  hipLaunchKernelGGL(k_qu, dim3(HU / 256), dim3(256), 0, stream,
                     invA, invB, qu, q_k0, q_k1);
  hipLaunchKernelGGL(k_klz_a, dim3(16), dim3(256), 0, stream, qu, Pch);
  hipLaunchKernelGGL(k_klz_b, dim3(16), dim3(256), 0, stream,
                     t_pi, qu, Pch, acc);
  hipLaunchKernelGGL(k_wbuildT, dim3(HEPS / 256), dim3(256), 0, stream,
                     mW, sW, t_pi, WzT, acc, e_k0, e_k1, u_k0, u_k1);
  hipLaunchKernelGGL(k_gemm, dim3(KU_N / GBN, B_N / GBM), dim3(256), 0, stream,
                     inputs, WzT, biases, out);
  hipLaunchKernelGGL(k_epi, dim3(8192 * 512 / 256), dim3(256), 0, stream,
                     out, partial, g_k0, g_k1);
  hipLaunchKernelGGL(k_final, dim3(1), dim3(256), 0, stream,
                     acc, partial, 16384, out + 16777216);
}

// Round 3
// 181.457 us; speedup vs baseline: 4.3853x; 1.1748x over previous
//
#include <hip/hip_runtime.h>
#include <stdint.h>
#include <math.h>

// ---------------- problem constants ----------------
#define B_N   16384
#define D_N   1024
#define K_N   512
#define KU_N  1024          // K*U
#define EPS_F 1e-8f
#define TEMP  0.67f
#define EULERC 0.5772156649015329f

#define HEPS  524288        // 2^19  (eps stream half)
#define HU    262144        // 2^18  (bernoulli/kumaraswamy stream half)
#define HG    8388608       // 2^23  (gumbel stream half)

typedef uint32_t u32;
typedef __attribute__((ext_vector_type(4))) float f32x4;
typedef __attribute__((ext_vector_type(8))) __bf16 bf16x8;

// ---------------- threefry2x32 (JAX-exact) ----------------
#define TF_ROT(x, r) (((x) << (r)) | ((x) >> (32 - (r))))

__host__ __device__ static inline void threefry2x32(u32 k0, u32 k1,
                                                    u32 x0, u32 x1,
                                                    u32* o0, u32* o1) {
  u32 ks2 = k0 ^ k1 ^ 0x1BD11BDAu;
  x0 += k0; x1 += k1;
  x0 += x1; x1 = TF_ROT(x1, 13); x1 ^= x0;
  x0 += x1; x1 = TF_ROT(x1, 15); x1 ^= x0;
  x0 += x1; x1 = TF_ROT(x1, 26); x1 ^= x0;
  x0 += x1; x1 = TF_ROT(x1, 6);  x1 ^= x0;
  x0 += k1; x1 += ks2 + 1u;
  x0 += x1; x1 = TF_ROT(x1, 17); x1 ^= x0;
  x0 += x1; x1 = TF_ROT(x1, 29); x1 ^= x0;
  x0 += x1; x1 = TF_ROT(x1, 16); x1 ^= x0;
  x0 += x1; x1 = TF_ROT(x1, 24); x1 ^= x0;
  x0 += ks2; x1 += k0 + 2u;
  x0 += x1; x1 = TF_ROT(x1, 13); x1 ^= x0;
  x0 += x1; x1 = TF_ROT(x1, 15); x1 ^= x0;
  x0 += x1; x1 = TF_ROT(x1, 26); x1 ^= x0;
  x0 += x1; x1 = TF_ROT(x1, 6);  x1 ^= x0;
  x0 += k0; x1 += k1 + 3u;
  x0 += x1; x1 = TF_ROT(x1, 17); x1 ^= x0;
  x0 += x1; x1 = TF_ROT(x1, 29); x1 ^= x0;
  x0 += x1; x1 = TF_ROT(x1, 16); x1 ^= x0;
  x0 += x1; x1 = TF_ROT(x1, 24); x1 ^= x0;
  x0 += k1; x1 += ks2 + 4u;
  x0 += x1; x1 = TF_ROT(x1, 13); x1 ^= x0;
  x0 += x1; x1 = TF_ROT(x1, 15); x1 ^= x0;
  x0 += x1; x1 = TF_ROT(x1, 26); x1 ^= x0;
  x0 += x1; x1 = TF_ROT(x1, 6);  x1 ^= x0;
  x0 += ks2; x1 += k0 + 5u;
  *o0 = x0; *o1 = x1;
}

// ---------------- numeric helpers ----------------
__device__ static inline float bits_to_u01(u32 b) {
  u32 f = (b >> 9) | 0x3f800000u;
  return __uint_as_float(f) - 1.0f;
}
__device__ static inline float unif_f(u32 b, float lo, float hi) {
  float f = bits_to_u01(b);
  return fmaxf(lo, f * (hi - lo) + lo);
}
__device__ static inline float erfinv_f(float x) {
  float w = -log1pf(-x * x);
  float p;
  if (w < 5.f) {
    w -= 2.5f;
    p = 2.81022636e-08f;
    p = fmaf(p, w, 3.43273939e-07f);
    p = fmaf(p, w, -3.5233877e-06f);
    p = fmaf(p, w, -4.39150654e-06f);
    p = fmaf(p, w, 0.00021858087f);
    p = fmaf(p, w, -0.00125372503f);
    p = fmaf(p, w, -0.00417768164f);
    p = fmaf(p, w, 0.246640727f);
    p = fmaf(p, w, 1.50140941f);
  } else {
    w = sqrtf(w) - 3.f;
    p = -0.000200214257f;
    p = fmaf(p, w, 0.000100950558f);
    p = fmaf(p, w, 0.00134934322f);
    p = fmaf(p, w, -0.00367342844f);
    p = fmaf(p, w, 0.00573950773f);
    p = fmaf(p, w, -0.0076224613f);
    p = fmaf(p, w, 0.00943887047f);
    p = fmaf(p, w, 1.00167406f);
    p = fmaf(p, w, 2.83297682f);
  }
  return p * x;
}
__device__ static inline float softplus_f(float x) {
  return fmaxf(x, 0.f) + log1pf(expf(-fabsf(x)));
}
__device__ static inline float rcp_f(float x) { return __builtin_amdgcn_rcpf(x); }
__device__ static inline float sigmoid_fast(float x) {
  return rcp_f(1.f + __expf(-x));
}
__device__ static inline float digamma_f(float x) {
  float r = 0.f;
  while (x < 6.f) { r -= 1.f / x; x += 1.f; }
  float inv = 1.f / x, inv2 = inv * inv;
  return r + logf(x) - 0.5f * inv
       - inv2 * (1.f / 12.f - inv2 * (1.f / 120.f - inv2 * (1.f / 252.f)));
}
__device__ static inline unsigned short f2bf_rne(float x) {
  u32 u = __float_as_uint(x);
  u32 r = (u + 0x7fffu + ((u >> 16) & 1u)) >> 16;
  return (unsigned short)r;
}
__device__ static inline u32 cvt_pk_bf16(float lo, float hi) {
  u32 r;
  asm("v_cvt_pk_bf16_f32 %0, %1, %2" : "=v"(r) : "v"(lo), "v"(hi));
  return r;
}
__device__ static inline void gload_lds16(const void* g, void* l) {
  __builtin_amdgcn_global_load_lds(
      (const __attribute__((address_space(1))) u32*)g,
      (__attribute__((address_space(3))) u32*)l, 16, 0, 0);
}

// block-wide sum; valid result only on thread 0
__device__ static inline float block_sum(float v) {
  __shared__ float sm[16];
  int lane = threadIdx.x & 63;
  int wid = threadIdx.x >> 6;
  #pragma unroll
  for (int o = 32; o > 0; o >>= 1) v += __shfl_down(v, o, 64);
  if (lane == 0) sm[wid] = v;
  __syncthreads();
  float s = 0.f;
  if (threadIdx.x == 0) {
    int nw = (blockDim.x + 63) >> 6;
    s = sm[0];
    for (int w = 1; w < nw; ++w) s += sm[w];
  }
  return s;
}

// ---------------- kernels ----------------
// init: per-k tables, kl_sticks -> gacc[1], zero gacc[0], gacc[2]
__global__ void k_init(const float* __restrict__ conc1,
                       const float* __restrict__ conc0,
                       float* __restrict__ invA, float* __restrict__ invB,
                       float* gacc) {
  int k = threadIdx.x;  // 512
  float a = softplus_f(conc1[k]);
  float b = softplus_f(conc0[k]);
  invA[k] = 1.f / a;
  invB[k] = 1.f / b;
  float s = ((a - 1.f) / a) * (-EULERC - digamma_f(b) - 1.f / b)
          + logf(a * b + EPS_F) - (b - 1.f) / b;
  float t = block_sum(s);
  if (threadIdx.x == 0) { gacc[0] = 0.f; gacc[1] = t; gacc[2] = 0.f; }
}

// kl_z pass A: 64 chunks of 16 d's; qu computed inline (threefry + pow)
__global__ __launch_bounds__(256) void k_klz_a(const float* __restrict__ invA,
                                               const float* __restrict__ invB,
                                               float* __restrict__ P,
                                               u32 qk0, u32 qk1) {
  int idx = blockIdx.x * 256 + threadIdx.x;  // [0, 32768)
  int c = idx >> 9, k = idx & (K_N - 1);
  float iA = invA[k], iB = invB[k];
  float p = 1.f;
  int d0 = c << 4;
  for (int d = d0; d < d0 + 16; ++d) {
    int n = (d << 9) + k;
    u32 x0 = (n < HU) ? (u32)n : (u32)(n - HU);
    u32 o0, o1;
    threefry2x32(qk0, qk1, x0, x0 + HU, &o0, &o1);
    u32 bits = (n < HU) ? o0 : o1;
    float u = unif_f(bits, 1e-6f, 1.f - 1e-6f);
    p *= powf(1.f - powf(u, iB), iA);
  }
  P[idx] = p;
}

// kl_z pass B: prefix-recombined cumprod + KL sum -> atomicAdd gacc[1]
__global__ __launch_bounds__(256) void k_klz_b(const float* __restrict__ t_pi,
                                               const float* __restrict__ invA,
                                               const float* __restrict__ invB,
                                               const float* __restrict__ P,
                                               float* gacc,
                                               u32 qk0, u32 qk1) {
  int idx = blockIdx.x * 256 + threadIdx.x;  // [0, 32768)
  int c = idx >> 9, k = idx & (K_N - 1);
  float iA = invA[k], iB = invB[k];
  float prior = 1.f;
  for (int c2 = 0; c2 < c; ++c2) prior *= P[(c2 << 9) + k];
  float s = 0.f;
  int d0 = c << 4;
  for (int d = d0; d < d0 + 16; ++d) {
    int n = (d << 9) + k;
    u32 x0 = (n < HU) ? (u32)n : (u32)(n - HU);
    u32 o0, o1;
    threefry2x32(qk0, qk1, x0, x0 + HU, &o0, &o1);
    u32 bits = (n < HU) ? o0 : o1;
    float u = unif_f(bits, 1e-6f, 1.f - 1e-6f);
    prior *= powf(1.f - powf(u, iB), iA);
    float q = sigmoid_fast(t_pi[n]);
    s += q * (__logf(q + EPS_F) - __logf(prior + EPS_F));
  }
  float t = block_sum(s);
  if (threadIdx.x == 0) atomicAdd(&gacc[1], t);
}

// WzT[j][d] = z(d, j%K)*(mW[d][j]+eps*softplus(sW[d][j])) in bf16, via 64x64
// LDS transpose tile (coalesced loads AND stores); kl_weights -> gacc[0]
__global__ __launch_bounds__(256) void k_wbuildT(const float* __restrict__ mW,
                                                 const float* __restrict__ sW,
                                                 const float* __restrict__ t_pi,
                                                 unsigned short* __restrict__ WzT,
                                                 float* __restrict__ gacc,
                                                 u32 ek0, u32 ek1,
                                                 u32 uk0, u32 uk1) {
  __shared__ unsigned short tile[64][65];
  int dt = (int)blockIdx.x >> 4;   // 0..15
  int jt = (int)blockIdx.x & 15;   // 0..15
  int d0 = dt << 6, j0 = jt << 6;
  int tj = threadIdx.x & 63;
  int tr = threadIdx.x >> 6;       // 0..3
  int j = j0 + tj;
  int kk = j & (K_N - 1);
  bool lowD = (dt < 8);
  float klw = 0.f;
  #pragma unroll 4
  for (int rr = 0; rr < 16; ++rr) {
    int dl = (rr << 2) + tr;
    int d = d0 + dl;
    int n = (d << 10) + j;
    u32 x0 = lowD ? (u32)n : (u32)(n - HEPS);
    u32 o0, o1;
    threefry2x32(ek0, ek1, x0, x0 + HEPS, &o0, &o1);
    u32 ebits = lowD ? o0 : o1;
    int nz = (d << 9) + kk;
    u32 zx0 = lowD ? (u32)nz : (u32)(nz - HU);
    u32 z0, z1;
    threefry2x32(uk0, uk1, zx0, zx0 + HU, &z0, &z1);
    u32 zbits = lowD ? z0 : z1;
    float u = unif_f(zbits, 1e-6f, 1.f - 1e-6f);
    float logistic = __logf(u) - log1pf(-u);
    float z = sigmoid_fast((t_pi[nz] + logistic) * (1.f / TEMP));
    float un = unif_f(ebits, -0.99999994f, 1.0f);
    float epsn = 1.41421356f * erfinv_f(un);
    float m = mW[n], sp = softplus_f(sW[n]);
    tile[tj][dl] = f2bf_rne(z * (m + epsn * sp));
    klw += 2.f * sp - m * m - sp * sp + 1.f;
  }
  __syncthreads();
  #pragma unroll 4
  for (int rr = 0; rr < 16; ++rr) {
    int jl = (rr << 2) + tr;
    WzT[(size_t)(j0 + jl) * D_N + d0 + tj] = tile[jl][tj];
  }
  float t = block_sum(klw);
  if (threadIdx.x == 0) atomicAdd(&gacc[0], t);
}

// ---------------- fused MFMA GEMM + LWTA epilogue ----------------
// Block covers rows {brow..brow+63} U {brow+8192..+63}, cols bcol..bcol+127.
#define GBN 128
#define GBK 32

__global__ __launch_bounds__(256) void k_gemm(const float* __restrict__ A,
                                              const unsigned short* __restrict__ Bt,
                                              const float* __restrict__ bias,
                                              float* __restrict__ C,
                                              float* __restrict__ gacc,
                                              u32 gk0, u32 gk1) {
  __shared__ float As[128 * GBK];            // 16KB
  __shared__ unsigned short Bs[GBN * GBK];   // 8KB

  // XCD-chunked swizzle: 8 consecutive works share an A panel on one XCD
  int f = (int)blockIdx.x;                   // 0..1023
  int wk = (f & 7) * 128 + (f >> 3);
  int by = wk >> 3;                          // 0..127
  int bxN = wk & 7;                          // 0..7
  const int brow = by * 64;
  const int bcol = bxN * GBN;

  const int tid = threadIdx.x;
  const int lane = tid & 63;
  const int w = tid >> 6;

  // A staging: row arr = tid>>3, 16B slot tid&7, pre-swizzled source chunk
  const int arr = tid >> 3;
  const int aco = ((tid & 7) ^ (arr & 7)) << 2;
  const float* gA0 = A + (size_t)(brow + arr) * D_N + aco;
  const float* gA1 = A + (size_t)(8192 + brow + arr) * D_N + aco;
  // B staging
  const int brr = tid >> 2;
  const int bco = ((tid & 3) ^ (brr & 3)) << 3;
  const unsigned short* gB = Bt + (size_t)(bcol + brr) * D_N + bco;

  f32x4 acc[4][4];
  #pragma unroll
  for (int m = 0; m < 4; ++m)
    #pragma unroll
    for (int n = 0; n < 4; ++n) acc[m][n] = (f32x4){0.f, 0.f, 0.f, 0.f};

  const int wr2 = (w >> 1) << 5;   // 0 or 32
  const int wc = (w & 1) << 6;     // 0 or 64
  const int fr = lane & 15;
  const int kg = lane >> 4;        // 0..3

  union BF8 { u32 u[4]; bf16x8 v; };

  for (int kt = 0; kt < D_N; kt += GBK) {
    gload_lds16(gA0 + kt,            (char*)As + 0 * 4096 + (w << 10));
    gload_lds16(gA0 + 32 * D_N + kt, (char*)As + 1 * 4096 + (w << 10));
    gload_lds16(gA1 + kt,            (char*)As + 2 * 4096 + (w << 10));
    gload_lds16(gA1 + 32 * D_N + kt, (char*)As + 3 * 4096 + (w << 10));
    gload_lds16(gB + kt,             (char*)Bs + 0 * 4096 + (w << 10));
    gload_lds16(gB + 64 * D_N + kt,  (char*)Bs + 1 * 4096 + (w << 10));
    __syncthreads();

    BF8 af[4];
    #pragma unroll
    for (int m = 0; m < 4; ++m) {
      int lr = (m < 2 ? wr2 + m * 16 : 64 + wr2 + (m - 2) * 16) + fr;
      int r7 = lr & 7;
      const float* pa = As + lr * GBK;
      f32x4 lov = *(const f32x4*)(pa + ((((kg << 1)    ) ^ r7) << 2));
      f32x4 hiv = *(const f32x4*)(pa + ((((kg << 1) | 1) ^ r7) << 2));
      af[m].u[0] = cvt_pk_bf16(lov.x, lov.y);
      af[m].u[1] = cvt_pk_bf16(lov.z, lov.w);
      af[m].u[2] = cvt_pk_bf16(hiv.x, hiv.y);
      af[m].u[3] = cvt_pk_bf16(hiv.z, hiv.w);
    }
    #pragma unroll
    for (int n = 0; n < 4; ++n) {
      int colL = wc + n * 16 + fr;
      bf16x8 bf = *(const bf16x8*)(Bs + colL * GBK + ((kg ^ (colL & 3)) << 3));
      #pragma unroll
      for (int m = 0; m < 4; ++m)
        acc[m][n] = __builtin_amdgcn_mfma_f32_16x16x32_bf16(af[m].v, bf, acc[m][n], 0, 0, 0);
    }
    __syncthreads();
  }

  // ---- fused LWTA epilogue: rows r (acc[0..1]) pair with r+8192 (acc[2..3])
  const float invT = 1.f / TEMP;
  const float LOG2F = 0.6931471805599453f;
  float klsum = 0.f;
  #pragma unroll
  for (int n = 0; n < 4; ++n) {
    int col = bcol + wc + n * 16 + fr;
    float bv = bias[col];
    #pragma unroll
    for (int m = 0; m < 2; ++m) {
      int r0 = brow + wr2 + m * 16 + (kg << 2);
      #pragma unroll
      for (int j = 0; j < 4; ++j) {
        float v0 = acc[m][n][j] + bv;        // logits at (r, col)
        float v1 = acc[m + 2][n][j] + bv;    // logits at (r+8192, col)
        int r = r0 + j;
        u32 midx = (u32)(r * KU_N + col);
        u32 b0, b1;
        threefry2x32(gk0, gk1, midx, midx + HG, &b0, &b1);
        float u0 = unif_f(b0, 1e-6f, 1.f - 1e-6f);
        float u1 = unif_f(b1, 1e-6f, 1.f - 1e-6f);
        float g0 = -__logf(-__logf(u0));
        float g1 = -__logf(-__logf(u1));
        float s0 = (v0 + g0) * invT;
        float s1 = (v1 + g1) * invT;
        float s0o = __shfl_xor(s0, 1, 64);
        float s1o = __shfl_xor(s1, 1, 64);
        float l0o = __shfl_xor(v0, 1, 64);
        float l1o = __shfl_xor(v1, 1, 64);
        float xi0 = rcp_f(1.f + __expf(s0o - s0));
        float xi1 = rcp_f(1.f + __expf(s1o - s1));
        C[(size_t)r * KU_N + col] = v0 * xi0;
        C[(size_t)(r + 8192) * KU_N + col] = v1 * xi1;
        float q0 = rcp_f(1.f + __expf(l0o - v0));
        float q1 = rcp_f(1.f + __expf(l1o - v1));
        klsum += q0 * (__logf(q0 + EPS_F) + LOG2F)
               + q1 * (__logf(q1 + EPS_F) + LOG2F);
      }
    }
  }
  float t = block_sum(klsum);
  if (threadIdx.x == 0) atomicAdd(&gacc[2], t);
}

__global__ void k_final(const float* __restrict__ gacc,
                        float* __restrict__ out_loss) {
  if (threadIdx.x == 0) {
    float kl_weights = -0.5f * (gacc[0] * (1.f / 1048576.f));
    out_loss[0] = kl_weights / 60000.f + gacc[1] + gacc[2] * (1.f / 16384.f);
  }
}

// ---------------- launch ----------------
extern "C" void kernel_launch(void* const* d_in, const int* in_sizes, int n_in,
                              void* d_out, int out_size, void* d_ws, size_t ws_size,
                              hipStream_t stream) {
  (void)in_sizes; (void)n_in; (void)out_size; (void)ws_size;
  const float* inputs = (const float*)d_in[0];
  const float* mW     = (const float*)d_in[1];
  const float* sW     = (const float*)d_in[2];
  const float* conc1  = (const float*)d_in[3];
  const float* conc0  = (const float*)d_in[4];
  const float* t_pi   = (const float*)d_in[5];
  const float* biases = (const float*)d_in[6];
  float* out = (float*)d_out;

  // rk[0..3] = split(key(42), 4)
  u32 a[4], b[4];
  for (int i = 0; i < 4; ++i)
    threefry2x32(0u, 42u, (u32)i, (u32)(i + 4), &a[i], &b[i]);
  u32 e_k0 = a[0], e_k1 = a[1];   // eps (normal)
  u32 u_k0 = a[2], u_k1 = a[3];   // bernoulli-u
  u32 q_k0 = b[0], q_k1 = b[1];   // kumaraswamy
  u32 g_k0 = b[2], g_k1 = b[3];   // gumbel

  char* wsb = (char*)d_ws;
  unsigned short* WzT = (unsigned short*)wsb;                   // 2MB
  float* P    = (float*)(wsb + (2u << 20));                     // 128KB
  float* invA = (float*)(wsb + (2u << 20) + (128u << 10));      // 2KB
  float* invB = (float*)(wsb + (2u << 20) + (130u << 10));      // 2KB
  float* gacc = (float*)(wsb + (2u << 20) + (132u << 10));      // 32B

  hipLaunchKernelGGL(k_init, dim3(1), dim3(512), 0, stream,
                     conc1, conc0, invA, invB, gacc);
  hipLaunchKernelGGL(k_klz_a, dim3(128), dim3(256), 0, stream,
                     invA, invB, P, q_k0, q_k1);
  hipLaunchKernelGGL(k_klz_b, dim3(128), dim3(256), 0, stream,
                     t_pi, invA, invB, P, gacc, q_k0, q_k1);
  hipLaunchKernelGGL(k_wbuildT, dim3(256), dim3(256), 0, stream,
                     mW, sW, t_pi, WzT, gacc, e_k0, e_k1, u_k0, u_k1);
  hipLaunchKernelGGL(k_gemm, dim3(1024), dim3(256), 0, stream,
                     inputs, WzT, biases, out, gacc, g_k0, g_k1);
  hipLaunchKernelGGL(k_final, dim3(1), dim3(64), 0, stream,
                     gacc, out + 16777216);
}